// Round 6
// baseline (291.479 us; speedup 1.0000x reference)
//
#include <hip/hip_runtime.h>

#define V 255
#define L 16
#define P 8
#define CLIPV 10.0f
#define CSTRIDE 256        // LDS column stride (floats)
#define UN 4               // units (waves) per 256-thread block

__device__ __forceinline__ float tanh_half_clip(float s) {
    // tanh(0.5 * clip(s, -10, 10)) = 1 - 2/(exp(clip(s))+1)
    float tt = fminf(fmaxf(s, -CLIPV), CLIPV);
    float e = __expf(tt);
    return 1.0f - __fdividef(2.0f, e + 1.0f);
}

__device__ __forceinline__ void even_compute(float (&e2)[L], float (&res)[L], bool clip) {
#pragma unroll
    for (int l = 0; l < L; ++l) if (e2[l] == 0.0f) e2[l] = 1.0f;
    float pre[L + 1];
    pre[0] = 1.0f;
#pragma unroll
    for (int l = 0; l < L; ++l) pre[l + 1] = pre[l] * e2[l];
    float suf = 1.0f;
#pragma unroll
    for (int l = L - 1; l >= 0; --l) {
        float r = pre[l] * suf;
        suf *= e2[l];
        if (clip) r = fminf(fmaxf(r, -CLIPV), CLIPV);
        res[l] = __logf(__fdividef(1.0f + r, 1.0f - r + 1e-9f) + 1e-9f);
    }
}

// One wave per (b,p) unit; lane handles v = lane + 64*j, j=0..3 (v=255 is a
// harmless dummy slot: written to row 255, never gathered -- gather rows are
// always mod 255). No __syncthreads anywhere: state is wave-private, DS ops
// are wave-ordered, gather-all-before-write handles in-place RAW.
template <int MODE>
__global__ __launch_bounds__(256, 2) void bpw_kernel(
    const float* __restrict__ x,
    const float* __restrict__ oddw_v,
    const float* __restrict__ oddw_e,
    const float* __restrict__ w_e_out,
    const int*   __restrict__ perma,
    const int*   __restrict__ rc_idx,
    const int*   __restrict__ cr_idx,
    float* __restrict__ eo_ws,     // MODE 0
    const int* __restrict__ invp,  // MODE 1
    float* __restrict__ out)       // MODE 1
{
    __shared__ float Sall[UN][L * CSTRIDE];   // 65.5 KB

    const int tid  = threadIdx.x;
    const int w    = tid >> 6;
    const int lane = tid & 63;
    float* __restrict__ S = Sall[w];
    const int unit = blockIdx.x * UN + w;     // (b,p)
    const int b = unit >> 3;
    const int p = unit & 7;

    // Wave-uniform rotation tables from the v=0 rows of rc/cr:
    //   rc_idx[l] = T_l*16 + m_l        (odd gather: col m_l, shift +T_l)
    //   cr_idx[l] = ((-T_k)%V)*16 + k   (even gather: col k, shift -T_k)
    // Uniform addresses -> compiler emits s_load (SGPR tables).
    int colO[L], shO[L], colE[L], shE[L];
#pragma unroll
    for (int l = 0; l < L; ++l) {
        int rc = rc_idx[l];
        colO[l] = (rc & 15) * CSTRIDE;
        shO[l]  = rc >> 4;
        int cr = cr_idx[l];
        colE[l] = (cr & 15) * CSTRIDE;
        shE[l]  = cr >> 4;
    }

    // Per-lane base offsets (j=0), wrapped into [0,V)
    int offO[L], offE[L];
#pragma unroll
    for (int l = 0; l < L; ++l) {
        int a = shO[l] + lane; offO[l] = (a >= V) ? a - V : a;
        int c = shE[l] + lane; offE[l] = (c >= V) ? c - V : c;
    }

    // per-lane x values (4 v's)
    float xv[4];
#pragma unroll
    for (int j = 0; j < 4; ++j) {
        int v = lane + 64 * j;
        xv[j] = (v < V) ? x[b * (V + 1) + perma[p * (V + 1) + v + 1]] : 0.0f;
    }

    // ---- t=0 odd layer: message==0 -> rank-1, write-only ----
#pragma unroll
    for (int m = 0; m < L; ++m) {
        float w0 = oddw_v[m];                 // uniform scalar load
#pragma unroll
        for (int j = 0; j < 4; ++j)
            S[m * CSTRIDE + lane + 64 * j] = tanh_half_clip(xv[j] * w0);
    }

#pragma unroll 1
    for (int t = 0; t < 5; ++t) {
        // ===== even layer (round t) =====
        float g0[L], g1[L], g2[L], g3[L];
#pragma unroll
        for (int l = 0; l < L; ++l) {
            int base = offE[l], cb = colE[l];
            int r1 = base + 64;  r1 -= (r1 >= V) ? V : 0;
            int r2 = base + 128; r2 -= (r2 >= V) ? V : 0;
            int r3 = base + 192; r3 -= (r3 >= V) ? V : 0;
            g0[l] = S[cb + base];
            g1[l] = S[cb + r1];
            g2[l] = S[cb + r2];
            g3[l] = S[cb + r3];
        }
        float o0[L], o1[L], o2[L], o3[L];
        even_compute(g0, o0, t == 0);
        even_compute(g1, o1, t == 0);
        even_compute(g2, o2, t == 0);
        even_compute(g3, o3, t == 0);
#pragma unroll
        for (int l = 0; l < L; ++l) {
            S[l * CSTRIDE + lane]       = o0[l];
            S[l * CSTRIDE + lane + 64]  = o1[l];
            S[l * CSTRIDE + lane + 128] = o2[l];
            S[l * CSTRIDE + lane + 192] = o3[l];
        }

        // ===== odd layer (round t+1) =====
        if (t < 4) {
            const float* __restrict__ wm = oddw_e + (t + 1) * (L * L);
            const float* __restrict__ wv = oddw_v + (t + 1) * L;

            float h0[L], h1[L], h2[L], h3[L];
#pragma unroll
            for (int l = 0; l < L; ++l) {
                int base = offO[l], cb = colO[l];
                int r1 = base + 64;  r1 -= (r1 >= V) ? V : 0;
                int r2 = base + 128; r2 -= (r2 >= V) ? V : 0;
                int r3 = base + 192; r3 -= (r3 >= V) ? V : 0;
                h0[l] = S[cb + base];
                h1[l] = S[cb + r1];
                h2[l] = S[cb + r2];
                h3[l] = S[cb + r3];
            }
            float a0[L], a1[L], a2[L], a3[L];
#pragma unroll
            for (int m = 0; m < L; ++m) {
                float wvm = wv[m];                // uniform scalar load
                a0[m] = xv[0] * wvm;
                a1[m] = xv[1] * wvm;
                a2[m] = xv[2] * wvm;
                a3[m] = xv[3] * wvm;
            }
#pragma unroll
            for (int l = 0; l < L; ++l) {
#pragma unroll
                for (int m = 0; m < L; ++m) {
                    if (m != l) {                 // diag masked (compile-time)
                        float wlm = wm[l * L + m];   // uniform scalar load
                        a0[m] = fmaf(h0[l], wlm, a0[m]);
                        a1[m] = fmaf(h1[l], wlm, a1[m]);
                        a2[m] = fmaf(h2[l], wlm, a2[m]);
                        a3[m] = fmaf(h3[l], wlm, a3[m]);
                    }
                }
            }
#pragma unroll
            for (int m = 0; m < L; ++m) {
                S[m * CSTRIDE + lane]       = tanh_half_clip(a0[m]);
                S[m * CSTRIDE + lane + 64]  = tanh_half_clip(a1[m]);
                S[m * CSTRIDE + lane + 128] = tanh_half_clip(a2[m]);
                S[m * CSTRIDE + lane + 192] = tanh_half_clip(a3[m]);
            }
        }
    }

    // ---- final: gather via rc, dot with w_e_out ----
    float d0 = 0.0f, d1 = 0.0f, d2 = 0.0f, d3 = 0.0f;
#pragma unroll
    for (int l = 0; l < L; ++l) {
        float wl = w_e_out[l];                    // uniform scalar load
        int base = offO[l], cb = colO[l];
        int r1 = base + 64;  r1 -= (r1 >= V) ? V : 0;
        int r2 = base + 128; r2 -= (r2 >= V) ? V : 0;
        int r3 = base + 192; r3 -= (r3 >= V) ? V : 0;
        d0 = fmaf(S[cb + base], wl, d0);
        d1 = fmaf(S[cb + r1], wl, d1);
        d2 = fmaf(S[cb + r2], wl, d2);
        d3 = fmaf(S[cb + r3], wl, d3);
    }
    if (MODE == 0) {
        float* eo = eo_ws + (size_t)unit * V;
        eo[lane]       = d0;
        eo[lane + 64]  = d1;
        eo[lane + 128] = d2;
        if (lane + 192 < V) eo[lane + 192] = d3;
    } else {
        float* orow = out + b * (V + 1);
        const int* irow = invp + p * (V + 1);
        atomicAdd(&orow[irow[lane + 1]], d0);
        atomicAdd(&orow[irow[lane + 65]], d1);
        atomicAdd(&orow[irow[lane + 129]], d2);
        if (lane + 192 < V) atomicAdd(&orow[irow[lane + 193]], d3);
    }
}

// gather-sum epilogue (MODE 0 path)
__global__ __launch_bounds__(256) void out_kernel(
    const float* __restrict__ x,
    const float* __restrict__ eo_ws,
    const int* __restrict__ perma,
    float* __restrict__ out)
{
    const int b = blockIdx.x;
    const int j = threadIdx.x;   // 0..255
    float acc = x[b * (V + 1) + j];
#pragma unroll
    for (int p = 0; p < P; ++p) {
        int idx = perma[p * (V + 1) + j];
        if (idx > 0) acc += eo_ws[((size_t)(b * P + p)) * V + (idx - 1)];
    }
    out[b * (V + 1) + j] = acc;
}

// fallback helpers (MODE 1 path)
__global__ __launch_bounds__(256) void inv_kernel(const int* __restrict__ perma,
                                                  int* __restrict__ invp)
{
    int p = blockIdx.x, j = threadIdx.x;
    invp[p * (V + 1) + perma[p * (V + 1) + j]] = j;
}

__global__ __launch_bounds__(256) void copy_kernel(const float* __restrict__ x,
                                                   float* __restrict__ out, int n)
{
    int i = blockIdx.x * 256 + threadIdx.x;
    if (i < n) out[i] = x[i];
}

extern "C" void kernel_launch(void* const* d_in, const int* in_sizes, int n_in,
                              void* d_out, int out_size, void* d_ws, size_t ws_size,
                              hipStream_t stream)
{
    const float* x       = (const float*)d_in[0];
    const float* oddw_v  = (const float*)d_in[2];
    const float* oddw_e  = (const float*)d_in[3];
    const float* w_e_out = (const float*)d_in[4];
    const int*   perma   = (const int*)d_in[5];
    const int*   rc      = (const int*)d_in[6];
    const int*   cr      = (const int*)d_in[7];
    float* out = (float*)d_out;

    const int Bx = in_sizes[0] / (V + 1);
    const int nunits = Bx * P;
    const int nblk = (nunits + UN - 1) / UN;
    const size_t need = (size_t)nunits * V * sizeof(float);

    if (ws_size >= need) {
        float* eo = (float*)d_ws;
        hipLaunchKernelGGL((bpw_kernel<0>), dim3(nblk), dim3(256), 0, stream,
                           x, oddw_v, oddw_e, w_e_out, perma, rc, cr,
                           eo, (const int*)nullptr, (float*)nullptr);
        hipLaunchKernelGGL(out_kernel, dim3(Bx), dim3(256), 0, stream,
                           x, eo, perma, out);
    } else {
        // atomic fallback: needs P*(V+1)*4 = 8KB workspace for inverse perm
        int* invp = (int*)d_ws;
        hipLaunchKernelGGL(inv_kernel, dim3(P), dim3(V + 1), 0, stream, perma, invp);
        hipLaunchKernelGGL(copy_kernel, dim3((out_size + 255) / 256), dim3(256), 0, stream,
                           x, out, out_size);
        hipLaunchKernelGGL((bpw_kernel<1>), dim3(nblk), dim3(256), 0, stream,
                           x, oddw_v, oddw_e, w_e_out, perma, rc, cr,
                           (float*)nullptr, invp, out);
    }
}

// Round 7
// 237.950 us; speedup vs baseline: 1.2250x; 1.2250x over previous
//
#include <hip/hip_runtime.h>

#define V 255
#define L 16
#define E (V*L)      // 4080
#define P 8
#define CLIPV 10.0f

typedef __attribute__((ext_vector_type(2))) float f32x2;

__device__ __forceinline__ f32x2 splat(float a) { return (f32x2){a, a}; }
__device__ __forceinline__ f32x2 pk_fma(f32x2 a, f32x2 b, f32x2 c) {
    return __builtin_elementwise_fma(a, b, c);
}

// tanh(0.5 * clip(s, -10, 10)) = 1 - 2/(exp(clip(s))+1), per component
__device__ __forceinline__ f32x2 tanh_half_clip_pk(f32x2 s) {
    f32x2 t = __builtin_elementwise_min(
                  __builtin_elementwise_max(s, splat(-CLIPV)), splat(CLIPV));
    f32x2 r;
    float ex = __expf(t.x); r.x = 1.0f - __fdividef(2.0f, ex + 1.0f);
    float ey = __expf(t.y); r.y = 1.0f - __fdividef(2.0f, ey + 1.0f);
    return r;
}

// Transposed layout: element (v,l) of the [V][L] state -> l*V + v.
__device__ __forceinline__ int tr_idx(int i) {
    return (i & (L - 1)) * V + (i >> 4);
}

// Two (b,p) units per thread, packed in f32x2 (.x = pA, .y = pB).
// LDS state interleaved: S[idx] = {unitA, unitB} -> one ds_read_b64 feeds both.
// message == 0 by construction -> t=0 odd layer is rank-1 (no gather/read).
template <int MODE>
__global__ __launch_bounds__(256, 3) void bpp_kernel(
    const float* __restrict__ x,
    const float* __restrict__ oddw_v,
    const float* __restrict__ oddw_e,
    const float* __restrict__ w_e_out,
    const int*   __restrict__ perma,
    const int*   __restrict__ rc_idx,
    const int*   __restrict__ cr_idx,
    float* __restrict__ eo_ws,     // MODE 0
    const int* __restrict__ invp,  // MODE 1
    float* __restrict__ out)       // MODE 1
{
    __shared__ f32x2 S[E];   // 32.6 KB

    const int tid = threadIdx.x;
    const int blk = blockIdx.x;        // 0 .. Bx*P/2-1
    const int b  = blk >> 2;
    const int pA = (blk & 3) * 2;
    const int pB = pA + 1;
    const int v = tid;                 // check-node index, active if v < V

    f32x2 xv = splat(0.0f);
    if (v < V) {
        const float* xrow = x + b * (V + 1);
        xv.x = xrow[perma[pA * (V + 1) + v + 1]];
        xv.y = xrow[perma[pB * (V + 1) + v + 1]];
    }

    int rci[L], cri[L];   // transposed LDS element indices (same for A and B)
    if (v < V) {
#pragma unroll
        for (int l = 0; l < L; ++l) {
            rci[l] = tr_idx(rc_idx[v * L + l]);
            cri[l] = tr_idx(cr_idx[v * L + l]);
        }
    }

    // ---- t=0 odd layer: rank-1, write-only ----
    if (v < V) {
#pragma unroll
        for (int m = 0; m < L; ++m) {
            float w0 = oddw_v[m];                  // uniform scalar load
            S[m * V + v] = tanh_half_clip_pk(xv * w0);
        }
    }
    __syncthreads();

#pragma unroll 1
    for (int t = 0; t < 5; ++t) {
        // ===== even layer (round t) =====
        // r = prod_{k!=l} e_k with |e_k| < 1  =>  |r| <= 0.9987, so the
        // reference's t=0 clip(r,+-10) is an identity (skipped), and
        // log((1+r)/(1-r+1e-9)+1e-9) == log(1+r) - log(1-r+1e-9) to ~1e-6.
        f32x2 e2[L];
        if (v < V) {
#pragma unroll
            for (int l = 0; l < L; ++l) {
                f32x2 q = S[cri[l]];               // one ds_read_b64
                q.x = (q.x == 0.0f) ? 1.0f : q.x;
                q.y = (q.y == 0.0f) ? 1.0f : q.y;
                e2[l] = q;
            }
        }
        __syncthreads();   // gathers done; S may be overwritten

        if (v < V) {
            f32x2 pre[L + 1];
            pre[0] = splat(1.0f);
#pragma unroll
            for (int l = 0; l < L; ++l) pre[l + 1] = pre[l] * e2[l];
            f32x2 suf = splat(1.0f);
#pragma unroll
            for (int l = L - 1; l >= 0; --l) {
                f32x2 r = pre[l] * suf;
                suf = suf * e2[l];
                f32x2 num = r + 1.0f;
                f32x2 den = (1.0f - r) + 1e-9f;
                f32x2 o;
                o.x = __logf(num.x) - __logf(den.x);
                o.y = __logf(num.y) - __logf(den.y);
                S[l * V + v] = o;                  // one ds_write_b64
            }
        }
        __syncthreads();   // even outputs complete

        // ===== odd layer (round t+1) =====
        if (t < 4) {
            const float* __restrict__ wm = oddw_e + (t + 1) * (L * L);
            const float* __restrict__ wv = oddw_v + (t + 1) * L;

            f32x2 eg[L];
            if (v < V) {
#pragma unroll
                for (int l = 0; l < L; ++l) eg[l] = S[rci[l]];  // ds_read_b64
            }
            __syncthreads();   // gathers done; S may be overwritten

            if (v < V) {
                f32x2 s[L];
#pragma unroll
                for (int m = 0; m < L; ++m) s[m] = xv * wv[m];  // pk_mul
#pragma unroll
                for (int l = 0; l < L; ++l) {
                    const f32x2 el = eg[l];
#pragma unroll
                    for (int m = 0; m < L; ++m) {
                        if (m != l) {              // diag masked (compile-time)
                            s[m] = pk_fma(el, splat(wm[l * L + m]), s[m]);
                        }
                    }
                }
#pragma unroll
                for (int m = 0; m < L; ++m)
                    S[m * V + v] = tanh_half_clip_pk(s[m]);
            }
            __syncthreads();   // odd outputs complete
        }
    }

    // ---- final: gather via rc, dot with w_e_out ----
    if (v < V) {
        f32x2 d = splat(0.0f);
#pragma unroll
        for (int l = 0; l < L; ++l)
            d = pk_fma(S[rci[l]], splat(w_e_out[l]), d);
        const int uA = blk * 2;
        if (MODE == 0) {
            eo_ws[(size_t)uA * V + v]       = d.x;
            eo_ws[(size_t)(uA + 1) * V + v] = d.y;
        } else {
            int ja = invp[pA * (V + 1) + (v + 1)];
            int jb = invp[pB * (V + 1) + (v + 1)];
            atomicAdd(&out[b * (V + 1) + ja], d.x);
            atomicAdd(&out[b * (V + 1) + jb], d.y);
        }
    }
}

// gather-sum epilogue (MODE 0 path)
__global__ __launch_bounds__(256) void out_kernel(
    const float* __restrict__ x,
    const float* __restrict__ eo_ws,
    const int* __restrict__ perma,
    float* __restrict__ out)
{
    const int b = blockIdx.x;
    const int j = threadIdx.x;   // 0..255
    float acc = x[b * (V + 1) + j];
#pragma unroll
    for (int p = 0; p < P; ++p) {
        int idx = perma[p * (V + 1) + j];
        if (idx > 0) acc += eo_ws[((size_t)(b * P + p)) * V + (idx - 1)];
    }
    out[b * (V + 1) + j] = acc;
}

// fallback helpers (MODE 1 path)
__global__ __launch_bounds__(256) void inv_kernel(const int* __restrict__ perma,
                                                  int* __restrict__ invp)
{
    int p = blockIdx.x, j = threadIdx.x;
    invp[p * (V + 1) + perma[p * (V + 1) + j]] = j;
}

__global__ __launch_bounds__(256) void copy_kernel(const float* __restrict__ x,
                                                   float* __restrict__ out, int n)
{
    int i = blockIdx.x * 256 + threadIdx.x;
    if (i < n) out[i] = x[i];
}

extern "C" void kernel_launch(void* const* d_in, const int* in_sizes, int n_in,
                              void* d_out, int out_size, void* d_ws, size_t ws_size,
                              hipStream_t stream)
{
    const float* x       = (const float*)d_in[0];
    const float* oddw_v  = (const float*)d_in[2];
    const float* oddw_e  = (const float*)d_in[3];
    const float* w_e_out = (const float*)d_in[4];
    const int*   perma   = (const int*)d_in[5];
    const int*   rc      = (const int*)d_in[6];
    const int*   cr      = (const int*)d_in[7];
    float* out = (float*)d_out;

    const int Bx = in_sizes[0] / (V + 1);
    const int nunits = Bx * P;
    const size_t need = (size_t)nunits * V * sizeof(float);

    if (ws_size >= need) {
        float* eo = (float*)d_ws;
        hipLaunchKernelGGL((bpp_kernel<0>), dim3(nunits / 2), dim3(256), 0, stream,
                           x, oddw_v, oddw_e, w_e_out, perma, rc, cr,
                           eo, (const int*)nullptr, (float*)nullptr);
        hipLaunchKernelGGL(out_kernel, dim3(Bx), dim3(256), 0, stream,
                           x, eo, perma, out);
    } else {
        // atomic fallback: needs P*(V+1)*4 = 8KB workspace for inverse perm
        int* invp = (int*)d_ws;
        hipLaunchKernelGGL(inv_kernel, dim3(P), dim3(V + 1), 0, stream, perma, invp);
        hipLaunchKernelGGL(copy_kernel, dim3((out_size + 255) / 256), dim3(256), 0, stream,
                           x, out, out_size);
        hipLaunchKernelGGL((bpp_kernel<1>), dim3(nunits / 2), dim3(256), 0, stream,
                           x, oddw_v, oddw_e, w_e_out, perma, rc, cr,
                           (float*)nullptr, invp, out);
    }
}